// Round 3
// baseline (1279.293 us; speedup 1.0000x reference)
//
#include <hip/hip_runtime.h>
#include <stdint.h>

typedef unsigned short u16;
typedef unsigned int u32;
typedef __attribute__((ext_vector_type(8))) short short8;   // 8 bf16 (4 VGPR)
typedef __attribute__((ext_vector_type(4))) float f32x4;

#define WAVES 6
#define NTHR 384
#define K2E16 0.09016844005556021f   /* log2(e)/16 : 1/sqrt(256) folded into exp2 */

static __device__ __forceinline__ u16 f2bf(float f) {
  union { float f; u32 u; } v; v.f = f;
  u32 r = v.u + 0x7FFFu + ((v.u >> 16) & 1u);   // RNE
  return (u16)(r >> 16);
}

// ---------------------------------------------------------------------------
// K0: weight prep.
//  - Wvo = Wv @ Wo (f32), stored bf16 in MFMA-B fragment layout (K=256)
//  - WqF/WkF: bf16 fragment layout (K=128)
//  - bvo = bv @ Wo + bo (f32)
// Fragment layout (16x16x32 B operand): for (k,col):
//   idx = ((kt*16 + nt)*64 + g*16 + (col&15))*8 + e, kt=k>>5, g=(k>>3)&3, e=k&7
// ---------------------------------------------------------------------------
__global__ __launch_bounds__(256) void k_setup(
    const float* __restrict__ Wq, const float* __restrict__ Wk,
    const float* __restrict__ Wv, const float* __restrict__ Wo,
    const float* __restrict__ bv, const float* __restrict__ bo,
    u16* __restrict__ WqF, u16* __restrict__ WkF, u16* __restrict__ WvoF,
    float* __restrict__ bvo) {
  const int ci = blockIdx.x;   // k-row
  const int co = threadIdx.x;  // col
  float acc = 0.f;
  for (int h = 0; h < 256; ++h)
    acc += Wv[ci*256 + h] * Wo[h*256 + co];
  const int idx = (((ci>>5)*16 + (co>>4))*64 + (((ci>>3)&3)*16 + (co&15)))*8 + (ci&7);
  WvoF[idx] = f2bf(acc);
  if (ci < 128) {
    WqF[idx] = f2bf(Wq[ci*256 + co]);
    WkF[idx] = f2bf(Wk[ci*256 + co]);
  }
  if (ci == 0) {
    float a2 = 0.f;
    for (int h = 0; h < 256; ++h) a2 += bv[h] * Wo[h*256 + co];
    bvo[co] = a2 + bo[co];
  }
}

// ---------------------------------------------------------------------------
// K2 (fully fused, one launch, grid (1024, 8)): per (b,n):
//   q = ste_dec@Wq+bq, k = ste_enc@Wk+bk  (bf16 MFMA -> LDS)
//   scoresT = mfma(K,Q)  (lane-local softmax column)
//   enc2 = bf16(enc)@Wvo kept in regs (acc2), scheduled alongside softmax
//   softmax with 1/sum FOLDED into the bf16 attn pack (af)
//   acc2 -> sigma-matched B-fragments in xL (16B conflict-free stores)
//   out = attn @ enc2 + bvo  (f32 stores)
// LDS: qL 48K | kL 48K | xL 48K (sd+se -> enc -> enc2 frags) | biases 3K
// ---------------------------------------------------------------------------
__global__ __launch_bounds__(NTHR) void k_attn(
    const float* __restrict__ sdec, const float* __restrict__ senc,
    const float* __restrict__ enc,
    const float* __restrict__ bq, const float* __restrict__ bk,
    const u16* __restrict__ WqF, const u16* __restrict__ WkF,
    const u16* __restrict__ WvoF, const float* __restrict__ bvo,
    float* __restrict__ out) {
  extern __shared__ char smem[];
  char* qL = smem;                       // 49152
  char* kL = smem + 49152;               // 49152
  char* xL = smem + 98304;               // 49152: sd+se, then enc, then enc2 frags
  float* bqL  = (float*)(smem + 147456);
  float* bkL  = (float*)(smem + 148480);
  float* bvoL = (float*)(smem + 149504);

  const int n = blockIdx.x, b = blockIdx.y;
  const int tid = threadIdx.x, wave = tid >> 6, lane = tid & 63;
  const int g = lane >> 4, c15 = lane & 15;

  char* sdL = xL;
  char* seL = xL + 24576;

  // ---- stage ste_dec / ste_enc rows (512B f32 -> 256B bf16, swizzled) ----
  for (int i = wave; i < 48; i += WAVES) {
    const int r = 2*i + (lane >> 5);
    const int cl = lane & 31;
    {
      const float4 v = *(const float4*)(sdec + ((size_t)((b*96 + r)*1024 + n))*128 + cl*4);
      u32 lo = (u32)f2bf(v.x) | ((u32)f2bf(v.y) << 16);
      u32 hi = (u32)f2bf(v.z) | ((u32)f2bf(v.w) << 16);
      u32* d = (u32*)(sdL + r*256 + ((cl*8) ^ ((r & 7) << 4)));
      d[0] = lo; d[1] = hi;
    }
    {
      const float4 v = *(const float4*)(senc + ((size_t)((b*96 + r)*1024 + n))*128 + cl*4);
      u32 lo = (u32)f2bf(v.x) | ((u32)f2bf(v.y) << 16);
      u32 hi = (u32)f2bf(v.z) | ((u32)f2bf(v.w) << 16);
      u32* d = (u32*)(seL + r*256 + ((cl*8) ^ ((r & 7) << 4)));
      d[0] = lo; d[1] = hi;
    }
  }
  if (tid < 256) { bqL[tid] = bq[tid]; bkL[tid] = bk[tid]; bvoL[tid] = bvo[tid]; }
  __syncthreads();

  // ---- q projection (M=96, K=128, N=256; waves partition N col-tiles) ----
  {
    f32x4 acc[3][6];
    #pragma unroll
    for (int i = 0; i < 3; ++i)
      #pragma unroll
      for (int mt = 0; mt < 6; ++mt) acc[i][mt] = (f32x4)0.f;
    #pragma unroll
    for (int kt = 0; kt < 4; ++kt) {
      short8 a[6];
      #pragma unroll
      for (int mt = 0; mt < 6; ++mt) {
        const int row = 16*mt + c15;
        a[mt] = *(const short8*)(sdL + row*256 + ((16*g + 64*kt) ^ ((row & 7) << 4)));
      }
      #pragma unroll
      for (int i = 0; i < 3; ++i) {
        const int nt = wave + 6*i;
        if (nt < 16) {
          const short8 bf = *(const short8*)(WqF + (size_t)((kt*16 + nt)*64 + lane)*8);
          #pragma unroll
          for (int mt = 0; mt < 6; ++mt)
            acc[i][mt] = __builtin_amdgcn_mfma_f32_16x16x32_bf16(a[mt], bf, acc[i][mt], 0, 0, 0);
        }
      }
    }
    #pragma unroll
    for (int i = 0; i < 3; ++i) {
      const int nt = wave + 6*i;
      if (nt < 16) {
        const float bqv = bqL[c15 + 16*nt];
        #pragma unroll
        for (int mt = 0; mt < 6; ++mt) {
          #pragma unroll
          for (int r = 0; r < 4; ++r) {
            const int row = 16*mt + 4*g + r;
            *(u16*)(qL + row*512 + ((2*c15 + 32*nt) ^ ((row & 7) << 4))) =
                f2bf(acc[i][mt][r] + bqv);
          }
        }
      }
    }
  }
  // ---- k projection ----
  {
    f32x4 acc[3][6];
    #pragma unroll
    for (int i = 0; i < 3; ++i)
      #pragma unroll
      for (int mt = 0; mt < 6; ++mt) acc[i][mt] = (f32x4)0.f;
    #pragma unroll
    for (int kt = 0; kt < 4; ++kt) {
      short8 a[6];
      #pragma unroll
      for (int mt = 0; mt < 6; ++mt) {
        const int row = 16*mt + c15;
        a[mt] = *(const short8*)(seL + row*256 + ((16*g + 64*kt) ^ ((row & 7) << 4)));
      }
      #pragma unroll
      for (int i = 0; i < 3; ++i) {
        const int nt = wave + 6*i;
        if (nt < 16) {
          const short8 bf = *(const short8*)(WkF + (size_t)((kt*16 + nt)*64 + lane)*8);
          #pragma unroll
          for (int mt = 0; mt < 6; ++mt)
            acc[i][mt] = __builtin_amdgcn_mfma_f32_16x16x32_bf16(a[mt], bf, acc[i][mt], 0, 0, 0);
        }
      }
    }
    #pragma unroll
    for (int i = 0; i < 3; ++i) {
      const int nt = wave + 6*i;
      if (nt < 16) {
        const float bkv = bkL[c15 + 16*nt];
        #pragma unroll
        for (int mt = 0; mt < 6; ++mt) {
          #pragma unroll
          for (int r = 0; r < 4; ++r) {
            const int row = 16*mt + 4*g + r;
            *(u16*)(kL + row*512 + ((2*c15 + 32*nt) ^ ((row & 7) << 4))) =
                f2bf(acc[i][mt][r] + bkv);
          }
        }
      }
    }
  }
  __syncthreads();   // q,k visible; sd/se dead -> xL reusable for enc staging

  // ---- stage enc rows (1KB f32 -> 512B bf16, swizzled) into xL ----
  for (int r = wave; r < 96; r += WAVES) {
    const float4 v = *(const float4*)(enc + ((size_t)((b*96 + r)*1024 + n))*256 + lane*4);
    u32 lo = (u32)f2bf(v.x) | ((u32)f2bf(v.y) << 16);
    u32 hi = (u32)f2bf(v.z) | ((u32)f2bf(v.w) << 16);
    u32* d = (u32*)(xL + r*512 + ((lane*8) ^ ((r & 7) << 4)));
    d[0] = lo; d[1] = hi;
  }
  __syncthreads();

  // ---- scoresT = K @ Q^T for this wave's 16 query columns ----
  f32x4 sac[6];
  #pragma unroll
  for (int pt = 0; pt < 6; ++pt) sac[pt] = (f32x4)0.f;
  const int qrow = 16*wave + c15;
  const int qx = (qrow & 7) << 4;
  #pragma unroll
  for (int kt = 0; kt < 8; ++kt) {
    const short8 qf = *(const short8*)(qL + qrow*512 + ((16*g + 64*kt) ^ qx));
    #pragma unroll
    for (int pt = 0; pt < 6; ++pt) {
      const int row = 16*pt + c15;
      const short8 kf = *(const short8*)(kL + row*512 + ((16*g + 64*kt) ^ ((row & 7) << 4)));
      sac[pt] = __builtin_amdgcn_mfma_f32_16x16x32_bf16(kf, qf, sac[pt], 0, 0, 0);
    }
  }

  // ---- enc2 = enc @ Wvo into regs (co-schedulable with softmax below) ----
  f32x4 acc2[3][6];
  #pragma unroll
  for (int i = 0; i < 3; ++i)
    #pragma unroll
    for (int mt = 0; mt < 6; ++mt) acc2[i][mt] = (f32x4)0.f;
  #pragma unroll
  for (int kt = 0; kt < 8; ++kt) {
    short8 a[6];
    #pragma unroll
    for (int mt = 0; mt < 6; ++mt) {
      const int row = 16*mt + c15;
      a[mt] = *(const short8*)(xL + row*512 + ((16*g + 64*kt) ^ ((row & 7) << 4)));
    }
    #pragma unroll
    for (int i = 0; i < 3; ++i) {
      const int nt = wave + 6*i;
      if (nt < 16) {
        const short8 bf = *(const short8*)(WvoF + (size_t)((kt*16 + nt)*64 + lane)*8);
        #pragma unroll
        for (int mt = 0; mt < 6; ++mt)
          acc2[i][mt] = __builtin_amdgcn_mfma_f32_16x16x32_bf16(a[mt], bf, acc2[i][mt], 0, 0, 0);
      }
    }
  }

  // ---- softmax over p; column qi = 16*wave + c15 lives in lanes {l, l^16, l^32} ----
  float m = sac[0][0];
  #pragma unroll
  for (int pt = 0; pt < 6; ++pt)
    #pragma unroll
    for (int r = 0; r < 4; ++r) m = fmaxf(m, sac[pt][r]);
  m = fmaxf(m, __shfl_xor(m, 16));
  m = fmaxf(m, __shfl_xor(m, 32));
  float s = 0.f;
  #pragma unroll
  for (int pt = 0; pt < 6; ++pt)
    #pragma unroll
    for (int r = 0; r < 4; ++r) {
      const float e = exp2f((sac[pt][r] - m) * K2E16);
      sac[pt][r] = e; s += e;
    }
  s += __shfl_xor(s, 16);
  s += __shfl_xor(s, 32);
  const float rs = 1.f / s;   // folded into the bf16 attn pack below

  // ---- attn A-fragments straight from regs (sigma packing; pure in-lane) ----
  short8 af[3];
  #pragma unroll
  for (int kb = 0; kb < 3; ++kb) {
    union { u32 u[4]; short8 v; } cv;
    cv.u[0] = (u32)f2bf(sac[2*kb][0]*rs)   | ((u32)f2bf(sac[2*kb][1]*rs)   << 16);
    cv.u[1] = (u32)f2bf(sac[2*kb][2]*rs)   | ((u32)f2bf(sac[2*kb][3]*rs)   << 16);
    cv.u[2] = (u32)f2bf(sac[2*kb+1][0]*rs) | ((u32)f2bf(sac[2*kb+1][1]*rs) << 16);
    cv.u[3] = (u32)f2bf(sac[2*kb+1][2]*rs) | ((u32)f2bf(sac[2*kb+1][3]*rs) << 16);
    af[kb] = cv.v;
  }
  __syncthreads();   // all enc reads (acc2 MFMA) done -> xL reusable for enc2 frags

  // ---- acc2 -> sigma-matched B-fragments in xL (16B conflict-free stores) ----
  #pragma unroll
  for (int i = 0; i < 3; ++i) {
    const int nt = wave + 6*i;
    if (nt < 16) {
      #pragma unroll
      for (int kb = 0; kb < 3; ++kb) {
        union { u32 u[4]; uint4 v; } o;
        o.u[0] = (u32)f2bf(acc2[i][2*kb][0])   | ((u32)f2bf(acc2[i][2*kb][1])   << 16);
        o.u[1] = (u32)f2bf(acc2[i][2*kb][2])   | ((u32)f2bf(acc2[i][2*kb][3])   << 16);
        o.u[2] = (u32)f2bf(acc2[i][2*kb+1][0]) | ((u32)f2bf(acc2[i][2*kb+1][1]) << 16);
        o.u[3] = (u32)f2bf(acc2[i][2*kb+1][2]) | ((u32)f2bf(acc2[i][2*kb+1][3]) << 16);
        *(uint4*)(xL + (((nt*3 + kb)*64 + lane) << 4)) = o.v;
      }
    }
  }
  __syncthreads();

  // ---- out = attn @ enc2; epilogue: + bvo; f32 store ----
  #pragma unroll
  for (int nt = 0; nt < 16; ++nt) {
    f32x4 oa = (f32x4)0.f;
    #pragma unroll
    for (int kb = 0; kb < 3; ++kb) {
      const short8 ef = *(const short8*)(xL + (((nt*3 + kb)*64 + lane) << 4));
      oa = __builtin_amdgcn_mfma_f32_16x16x32_bf16(af[kb], ef, oa, 0, 0, 0);
    }
    const int c = c15 + 16*nt;
    const float bz = bvoL[c];
    #pragma unroll
    for (int r = 0; r < 4; ++r) {
      const int qi = 16*wave + 4*g + r;
      out[((size_t)((b*96 + qi)*1024 + n))*256 + c] = oa[r] + bz;
    }
  }
}

// ---------------------------------------------------------------------------
extern "C" void kernel_launch(void* const* d_in, const int* in_sizes, int n_in,
                              void* d_out, int out_size, void* d_ws, size_t ws_size,
                              hipStream_t stream) {
  const float* enc     = (const float*)d_in[0];
  const float* ste_enc = (const float*)d_in[1];
  const float* ste_dec = (const float*)d_in[2];
  const float* Wq = (const float*)d_in[3];
  const float* bq = (const float*)d_in[4];
  const float* Wk = (const float*)d_in[5];
  const float* bk = (const float*)d_in[6];
  const float* Wv = (const float*)d_in[7];
  const float* bv = (const float*)d_in[8];
  const float* Wo = (const float*)d_in[9];
  const float* bo = (const float*)d_in[10];
  float* out = (float*)d_out;

  u16*   WqF   = (u16*)d_ws;                              // 65536 B
  u16*   WkF   = (u16*)((char*)d_ws + 65536);             // 65536 B
  u16*   WvoF  = (u16*)((char*)d_ws + 131072);            // 131072 B
  float* bvo   = (float*)((char*)d_ws + 262144);          // 1024 B

  (void)hipFuncSetAttribute((const void*)k_attn,
        hipFuncAttributeMaxDynamicSharedMemorySize, 150528);

  k_setup<<<dim3(256), dim3(256), 0, stream>>>(Wq, Wk, Wv, Wo, bv, bo,
                                               WqF, WkF, WvoF, bvo);
  k_attn<<<dim3(1024, 8), dim3(NTHR), 150528, stream>>>(ste_dec, ste_enc, enc,
                                                        bq, bk, WqF, WkF, WvoF,
                                                        bvo, out);
}

// Round 4
// 1110.708 us; speedup vs baseline: 1.1518x; 1.1518x over previous
//
#include <hip/hip_runtime.h>
#include <stdint.h>

typedef unsigned short u16;
typedef unsigned int u32;
typedef __attribute__((ext_vector_type(8))) short short8;   // 8 bf16 (4 VGPR)
typedef __attribute__((ext_vector_type(4))) float f32x4;

#define WAVES 6
#define NTHR 384
#define K2E16 0.09016844005556021f   /* log2(e)/16 : 1/sqrt(256) folded into exp2 */

// LDS map (total 80384 B -> 2 blocks/CU)
#define SE_OFF    0          // senc bf16 [96][256B]      (24576)
#define ENC_OFF   24576      // enc half bf16 [96][256B]  (24576)
#define KW_OFF    49152      // KWE bf16 [96][304B]       (29184)
#define KW_STRIDE 304
#define BVO_OFF   78336      // f32[256]
#define BKQ_OFF   79360      // f32[144] (+pad)
#define LDS_TOTAL 80384
#define FRAG_OFF  0          // sigma-frag buffer (48K) overlays seL+encL

static __device__ __forceinline__ u16 f2bf(float f) {
  union { float f; u32 u; } v; v.f = f;
  u32 r = v.u + 0x7FFFu + ((v.u >> 16) & 1u);   // RNE
  return (u16)(r >> 16);
}
static __device__ __forceinline__ float bf2f(u16 x) {
  union { u32 u; float f; } v; v.u = ((u32)x) << 16; return v.f;
}

// ---------------------------------------------------------------------------
// K0: weight prep.
//  - WkqE[de][c] : c<128 -> sum_h Wk[de][h]*Wq[c][h]; c==128 -> sum_h Wk[de][h]*bq[h];
//                  c in 129..143 -> 0.  Stored bf16 as MFMA B-frags (K=128, 9 nt).
//  - bkqE[c]     : c<128 -> sum_h bk[h]*Wq[c][h]; c==128 -> bk.bq; else 0. (f32)
//  - WvoF  = bf16 frags of Wv@Wo (K=256, 16 nt), bvo = bv@Wo + bo (f32).
// ---------------------------------------------------------------------------
__global__ __launch_bounds__(256) void k_setup(
    const float* __restrict__ Wq, const float* __restrict__ Wk,
    const float* __restrict__ Wv, const float* __restrict__ Wo,
    const float* __restrict__ bq, const float* __restrict__ bk,
    const float* __restrict__ bv, const float* __restrict__ bo,
    u16* __restrict__ WkqF, float* __restrict__ bkqE,
    u16* __restrict__ WvoF, float* __restrict__ bvo) {
  const int ci = blockIdx.x;   // row (de for Wkq; enc-channel for Wvo)
  const int co = threadIdx.x;  // col
  // Wvo
  float acc = 0.f;
  for (int h = 0; h < 256; ++h) acc += Wv[ci*256 + h] * Wo[h*256 + co];
  const int idxv = (((ci>>5)*16 + (co>>4))*64 + (((ci>>3)&3)*16 + (co&15)))*8 + (ci&7);
  WvoF[idxv] = f2bf(acc);
  // WkqE (ci<128 rows, 144 cols)
  if (ci < 128 && co < 144) {
    float a = 0.f;
    if (co < 128) { for (int h = 0; h < 256; ++h) a += Wk[ci*256 + h] * Wq[co*256 + h]; }
    else if (co == 128) { for (int h = 0; h < 256; ++h) a += Wk[ci*256 + h] * bq[h]; }
    const int idx = (((ci>>5)*9 + (co>>4))*64 + (((ci>>3)&3)*16 + (co&15)))*8 + (ci&7);
    WkqF[idx] = f2bf(a);
  }
  if (ci == 0) {
    float a2 = 0.f;
    for (int h = 0; h < 256; ++h) a2 += bv[h] * Wo[h*256 + co];
    bvo[co] = a2 + bo[co];
    if (co < 144) {
      float bb = 0.f;
      if (co < 128)      { for (int h = 0; h < 256; ++h) bb += bk[h] * Wq[co*256 + h]; }
      else if (co == 128){ for (int h = 0; h < 256; ++h) bb += bk[h] * bq[h]; }
      bkqE[co] = bb;
    }
  }
}

// ---------------------------------------------------------------------------
// K2 fused, grid (1024, 8), 6 waves, 80384B LDS (2 blocks/CU):
//   KWE = bf16(senc) @ WkqE (+bkq)          -> kwL          (96x144, K=128)
//   scoresT = KWE[:, :128] @ sdecT + kbq    sdec frags DIRECT from global
//   softmax (1/sum folded into bf16 attn pack)
//   enc2 = bf16(enc)@Wvo in regs, two K-half passes (encL restaged)
//   acc2 -> sigma-matched B-frags over seL+encL; out = attn@enc2 + bvo
// ---------------------------------------------------------------------------
__global__ __launch_bounds__(NTHR, 3) void k_attn(
    const float* __restrict__ sdec, const float* __restrict__ senc,
    const float* __restrict__ enc,
    const u16* __restrict__ WkqF, const float* __restrict__ bkqE,
    const u16* __restrict__ WvoF, const float* __restrict__ bvo,
    float* __restrict__ out) {
  extern __shared__ char smem[];
  char* seL   = smem + SE_OFF;
  char* encL  = smem + ENC_OFF;
  char* kwL   = smem + KW_OFF;
  float* bvoL = (float*)(smem + BVO_OFF);
  float* bkqL = (float*)(smem + BKQ_OFF);
  char* fragL = smem + FRAG_OFF;

  const int n = blockIdx.x, b = blockIdx.y;
  const int tid = threadIdx.x, wave = tid >> 6, lane = tid & 63;
  const int g = lane >> 4, c15 = lane & 15;

  // ---- early: issue sdec B-frag loads (wave's own 16 q-rows; regs to P2) ----
  const float* sdp = sdec + ((size_t)((b*96 + 16*wave + c15)*1024 + n))*128 + 8*g;
  float4 sdv[4][2];
  #pragma unroll
  for (int kt = 0; kt < 4; ++kt) {
    sdv[kt][0] = *(const float4*)(sdp + 32*kt);
    sdv[kt][1] = *(const float4*)(sdp + 32*kt + 4);
  }

  // ---- P0: stage seL (senc bf16) and encL half-1 (enc d<128) ----
  for (int i = wave; i < 48; i += WAVES) {
    const int r = 2*i + (lane >> 5);
    const int cl = lane & 31;
    const float4 v = *(const float4*)(senc + ((size_t)((b*96 + r)*1024 + n))*128 + cl*4);
    u32 lo = (u32)f2bf(v.x) | ((u32)f2bf(v.y) << 16);
    u32 hi = (u32)f2bf(v.z) | ((u32)f2bf(v.w) << 16);
    u32* d = (u32*)(seL + r*256 + ((cl*8) ^ ((r & 7) << 4)));
    d[0] = lo; d[1] = hi;
  }
  for (int i = wave; i < 48; i += WAVES) {
    const int r = 2*i + (lane >> 5);
    const int cl = lane & 31;
    const float4 v = *(const float4*)(enc + ((size_t)((b*96 + r)*1024 + n))*256 + cl*4);
    u32 lo = (u32)f2bf(v.x) | ((u32)f2bf(v.y) << 16);
    u32 hi = (u32)f2bf(v.z) | ((u32)f2bf(v.w) << 16);
    u32* d = (u32*)(encL + r*256 + ((cl*8) ^ ((r & 7) << 4)));
    d[0] = lo; d[1] = hi;
  }
  if (tid < 256) bvoL[tid] = bvo[tid];
  if (tid < 144) bkqL[tid] = bkqE[tid];
  __syncthreads();

  // convert sdec loads -> bf16 B-frags (frees 16 VGPR)
  short8 sdf[4];
  #pragma unroll
  for (int kt = 0; kt < 4; ++kt) {
    union { u32 u[4]; short8 v; } cv;
    cv.u[0] = (u32)f2bf(sdv[kt][0].x) | ((u32)f2bf(sdv[kt][0].y) << 16);
    cv.u[1] = (u32)f2bf(sdv[kt][0].z) | ((u32)f2bf(sdv[kt][0].w) << 16);
    cv.u[2] = (u32)f2bf(sdv[kt][1].x) | ((u32)f2bf(sdv[kt][1].y) << 16);
    cv.u[3] = (u32)f2bf(sdv[kt][1].z) | ((u32)f2bf(sdv[kt][1].w) << 16);
    sdf[kt] = cv.v;
  }

  // ---- P1: KWE = seL @ WkqE (+bkq) -> kwL (9 nt over 6 waves) ----
  {
    f32x4 acc[2][6];
    #pragma unroll
    for (int j = 0; j < 2; ++j)
      #pragma unroll
      for (int mt = 0; mt < 6; ++mt) acc[j][mt] = (f32x4)0.f;
    #pragma unroll
    for (int kt = 0; kt < 4; ++kt) {
      short8 a[6];
      #pragma unroll
      for (int mt = 0; mt < 6; ++mt) {
        const int row = 16*mt + c15;
        a[mt] = *(const short8*)(seL + row*256 + ((16*g + 64*kt) ^ ((row & 7) << 4)));
      }
      #pragma unroll
      for (int j = 0; j < 2; ++j) {
        const int nt = wave + 6*j;
        if (nt < 9) {
          const short8 bf = *(const short8*)(WkqF + (size_t)((kt*9 + nt)*64 + lane)*8);
          #pragma unroll
          for (int mt = 0; mt < 6; ++mt)
            acc[j][mt] = __builtin_amdgcn_mfma_f32_16x16x32_bf16(a[mt], bf, acc[j][mt], 0, 0, 0);
        }
      }
    }
    #pragma unroll
    for (int j = 0; j < 2; ++j) {
      const int nt = wave + 6*j;
      if (nt < 9) {
        const float bb = bkqL[c15 + 16*nt];
        #pragma unroll
        for (int mt = 0; mt < 6; ++mt) {
          #pragma unroll
          for (int r = 0; r < 4; ++r) {
            const int p = 16*mt + 4*g + r;
            *(u16*)(kwL + p*KW_STRIDE + 2*(c15 + 16*nt)) = f2bf(acc[j][mt][r] + bb);
          }
        }
      }
    }
  }
  __syncthreads();

  // ---- P2: scoresT = KWE[:, :128] @ sdecT  (+ kbq), softmax, af pack ----
  f32x4 sac[6];
  #pragma unroll
  for (int pt = 0; pt < 6; ++pt) sac[pt] = (f32x4)0.f;
  #pragma unroll
  for (int kt = 0; kt < 4; ++kt) {
    #pragma unroll
    for (int pt = 0; pt < 6; ++pt) {
      const int row = 16*pt + c15;
      const short8 kf = *(const short8*)(kwL + row*KW_STRIDE + 16*g + 64*kt);
      sac[pt] = __builtin_amdgcn_mfma_f32_16x16x32_bf16(kf, sdf[kt], sac[pt], 0, 0, 0);
    }
  }
  #pragma unroll
  for (int pt = 0; pt < 6; ++pt)
    #pragma unroll
    for (int r = 0; r < 4; ++r) {
      const int p = 16*pt + 4*g + r;
      sac[pt][r] += bf2f(*(const u16*)(kwL + p*KW_STRIDE + 256));
    }

  float m = sac[0][0];
  #pragma unroll
  for (int pt = 0; pt < 6; ++pt)
    #pragma unroll
    for (int r = 0; r < 4; ++r) m = fmaxf(m, sac[pt][r]);
  m = fmaxf(m, __shfl_xor(m, 16));
  m = fmaxf(m, __shfl_xor(m, 32));
  float s = 0.f;
  #pragma unroll
  for (int pt = 0; pt < 6; ++pt)
    #pragma unroll
    for (int r = 0; r < 4; ++r) {
      const float e = exp2f((sac[pt][r] - m) * K2E16);
      sac[pt][r] = e; s += e;
    }
  s += __shfl_xor(s, 16);
  s += __shfl_xor(s, 32);
  const float rs = 1.f / s;

  short8 af[3];
  #pragma unroll
  for (int kb = 0; kb < 3; ++kb) {
    union { u32 u[4]; short8 v; } cv;
    cv.u[0] = (u32)f2bf(sac[2*kb][0]*rs)   | ((u32)f2bf(sac[2*kb][1]*rs)   << 16);
    cv.u[1] = (u32)f2bf(sac[2*kb][2]*rs)   | ((u32)f2bf(sac[2*kb][3]*rs)   << 16);
    cv.u[2] = (u32)f2bf(sac[2*kb+1][0]*rs) | ((u32)f2bf(sac[2*kb+1][1]*rs) << 16);
    cv.u[3] = (u32)f2bf(sac[2*kb+1][2]*rs) | ((u32)f2bf(sac[2*kb+1][3]*rs) << 16);
    af[kb] = cv.v;
  }

  // ---- P2b: enc2 pass1 (kt 0..3 from encL half-1) ----
  f32x4 acc2[3][6];
  #pragma unroll
  for (int i = 0; i < 3; ++i)
    #pragma unroll
    for (int mt = 0; mt < 6; ++mt) acc2[i][mt] = (f32x4)0.f;
  #pragma unroll
  for (int kt = 0; kt < 4; ++kt) {
    short8 a[6];
    #pragma unroll
    for (int mt = 0; mt < 6; ++mt) {
      const int row = 16*mt + c15;
      a[mt] = *(const short8*)(encL + row*256 + ((16*g + 64*kt) ^ ((row & 7) << 4)));
    }
    #pragma unroll
    for (int i = 0; i < 3; ++i) {
      const int nt = wave + 6*i;
      if (nt < 16) {
        const short8 bf = *(const short8*)(WvoF + (size_t)((kt*16 + nt)*64 + lane)*8);
        #pragma unroll
        for (int mt = 0; mt < 6; ++mt)
          acc2[i][mt] = __builtin_amdgcn_mfma_f32_16x16x32_bf16(a[mt], bf, acc2[i][mt], 0, 0, 0);
      }
    }
  }
  __syncthreads();   // all encL half-1 reads done

  // ---- P3: restage encL with enc half-2 (d 128..255) ----
  for (int i = wave; i < 48; i += WAVES) {
    const int r = 2*i + (lane >> 5);
    const int cl = lane & 31;
    const float4 v = *(const float4*)(enc + ((size_t)((b*96 + r)*1024 + n))*256 + 128 + cl*4);
    u32 lo = (u32)f2bf(v.x) | ((u32)f2bf(v.y) << 16);
    u32 hi = (u32)f2bf(v.z) | ((u32)f2bf(v.w) << 16);
    u32* d = (u32*)(encL + r*256 + ((cl*8) ^ ((r & 7) << 4)));
    d[0] = lo; d[1] = hi;
  }
  __syncthreads();

  // ---- P4: enc2 pass2 (kt 4..7) ----
  #pragma unroll
  for (int kt = 4; kt < 8; ++kt) {
    short8 a[6];
    #pragma unroll
    for (int mt = 0; mt < 6; ++mt) {
      const int row = 16*mt + c15;
      a[mt] = *(const short8*)(encL + row*256 + ((16*g + 64*(kt-4)) ^ ((row & 7) << 4)));
    }
    #pragma unroll
    for (int i = 0; i < 3; ++i) {
      const int nt = wave + 6*i;
      if (nt < 16) {
        const short8 bf = *(const short8*)(WvoF + (size_t)((kt*16 + nt)*64 + lane)*8);
        #pragma unroll
        for (int mt = 0; mt < 6; ++mt)
          acc2[i][mt] = __builtin_amdgcn_mfma_f32_16x16x32_bf16(a[mt], bf, acc2[i][mt], 0, 0, 0);
      }
    }
  }
  __syncthreads();   // all encL reads done -> frag region writable

  // ---- P5: acc2 -> sigma-matched B-frags over seL+encL ----
  #pragma unroll
  for (int i = 0; i < 3; ++i) {
    const int nt = wave + 6*i;
    if (nt < 16) {
      #pragma unroll
      for (int kb = 0; kb < 3; ++kb) {
        union { u32 u[4]; uint4 v; } o;
        o.u[0] = (u32)f2bf(acc2[i][2*kb][0])   | ((u32)f2bf(acc2[i][2*kb][1])   << 16);
        o.u[1] = (u32)f2bf(acc2[i][2*kb][2])   | ((u32)f2bf(acc2[i][2*kb][3])   << 16);
        o.u[2] = (u32)f2bf(acc2[i][2*kb+1][0]) | ((u32)f2bf(acc2[i][2*kb+1][1]) << 16);
        o.u[3] = (u32)f2bf(acc2[i][2*kb+1][2]) | ((u32)f2bf(acc2[i][2*kb+1][3]) << 16);
        *(uint4*)(fragL + (((nt*3 + kb)*64 + lane) << 4)) = o.v;
      }
    }
  }
  __syncthreads();

  // ---- P6: out = attn @ enc2 + bvo; f32 store ----
  #pragma unroll
  for (int nt = 0; nt < 16; ++nt) {
    f32x4 oa = (f32x4)0.f;
    #pragma unroll
    for (int kb = 0; kb < 3; ++kb) {
      const short8 ef = *(const short8*)(fragL + (((nt*3 + kb)*64 + lane) << 4));
      oa = __builtin_amdgcn_mfma_f32_16x16x32_bf16(af[kb], ef, oa, 0, 0, 0);
    }
    const int c = c15 + 16*nt;
    const float bz = bvoL[c];
    #pragma unroll
    for (int r = 0; r < 4; ++r) {
      const int qi = 16*wave + 4*g + r;
      out[((size_t)((b*96 + qi)*1024 + n))*256 + c] = oa[r] + bz;
    }
  }
}

// ---------------------------------------------------------------------------
extern "C" void kernel_launch(void* const* d_in, const int* in_sizes, int n_in,
                              void* d_out, int out_size, void* d_ws, size_t ws_size,
                              hipStream_t stream) {
  const float* enc     = (const float*)d_in[0];
  const float* ste_enc = (const float*)d_in[1];
  const float* ste_dec = (const float*)d_in[2];
  const float* Wq = (const float*)d_in[3];
  const float* bq = (const float*)d_in[4];
  const float* Wk = (const float*)d_in[5];
  const float* bk = (const float*)d_in[6];
  const float* Wv = (const float*)d_in[7];
  const float* bv = (const float*)d_in[8];
  const float* Wo = (const float*)d_in[9];
  const float* bo = (const float*)d_in[10];
  float* out = (float*)d_out;

  u16*   WkqF = (u16*)d_ws;                               // 36864 B
  u16*   WvoF = (u16*)((char*)d_ws + 36864);              // 131072 B -> 167936
  float* bvo  = (float*)((char*)d_ws + 167936);           // 1024 B   -> 168960
  float* bkqE = (float*)((char*)d_ws + 168960);           // 576 B

  (void)hipFuncSetAttribute((const void*)k_attn,
        hipFuncAttributeMaxDynamicSharedMemorySize, LDS_TOTAL);

  k_setup<<<dim3(256), dim3(256), 0, stream>>>(Wq, Wk, Wv, Wo, bq, bk, bv, bo,
                                               WkqF, bkqE, WvoF, bvo);
  k_attn<<<dim3(1024, 8), dim3(NTHR), LDS_TOTAL, stream>>>(
      ste_dec, ste_enc, enc, WkqF, bkqE, WvoF, bvo, out);
}